// Round 9
// baseline (424.370 us; speedup 1.0000x reference)
//
#include <hip/hip_runtime.h>
#include <stdint.h>

// y[b,o,w] = relu(bias[o] + sum_{i,kh} W[o,i,kh] * x[b,i,kh,w])
// q=i&3 split: q<2 ("rep") -> pre-sum W over tt => K=512; q>=2 ("pos") keeps
// the gathered K=8192. r21: single-kernel fusion WITHOUT cooperative launch
// (r20's coop launch silently no-op'd under graph capture -> out stayed 0).
//   * normal <<<512,256>>> launch; 512 = exactly 2 blocks/CU x 256 CU
//     (LDS 66.5KB caps residency at 2/CU; __launch_bounds__(256,2)) -> all
//     blocks co-resident -> software global barrier is safe.
//   * barrier: __device__ counters (zeroed at module load), each block
//     resets the OTHER counter before arriving (self-cleaning across graph
//     replays); __threadfence() release before arrive (waitcnt+wbl2),
//     __threadfence() acquire after release (inv) -> cross-XCD visibility
//     of Wb/W1b/f1t/idx.
//   * out zeroing moved to host hipMemsetAsync (graph-legal, memory-side;
//     kills the dirty-zero-line vs atomics-at-MALL hazard).
// Phase 2 gemm = r17 verbatim (58us best measured; m=f&7 XCD colocation).
// 1 kernel + 1 memset replaces 3 kernels.

#define NDIM 1024
#define TK   16
#define KPOS 8192    // pos K: 512 i's * 16 kh
#define KREP 512     // rep K: 32 (nl,q) * 16 kh
#define NCOL 2048    // 64 batches * 32 width
#define NBLK 512     // grid size == co-residency capacity

typedef unsigned short u16;
typedef uint32_t u32;
typedef u16   u16x8  __attribute__((ext_vector_type(8)));
typedef __bf16 bf16x8 __attribute__((ext_vector_type(8)));
typedef float  f32x4  __attribute__((ext_vector_type(4)));

__device__ int g_ctr1, g_ctr2;   // .bss -> zero at module load

__device__ __forceinline__ u16 f2bf(float x) {
    union { float f; unsigned u; } v; v.f = x;
    unsigned r = 0x7FFFu + ((v.u >> 16) & 1u);   // round-to-nearest-even
    return (u16)((v.u + r) >> 16);
}

// async global->LDS, 16B/lane; LDS dest is wave-uniform base + lane*16
__device__ __forceinline__ void load_lds_16B(const u16* g, u16* l) {
    __builtin_amdgcn_global_load_lds(
        (__attribute__((address_space(1))) void*)(uintptr_t)g,
        (__attribute__((address_space(3))) void*)(unsigned)(uintptr_t)l,
        16, 0, 0);
}

// device-wide barrier for exactly NBLK co-resident blocks.
// resetOther: counter of the *other* barrier, cleaned for the next use/launch
// (all resets complete before any block passes: store precedes add in program
// order; passing requires observing all NBLK release-adds).
__device__ __forceinline__ void global_barrier(int* arrive, int* resetOther) {
    __threadfence();                     // release: drain + wbl2
    __syncthreads();
    if (threadIdx.x == 0) {
        __hip_atomic_store(resetOther, 0, __ATOMIC_RELAXED,
                           __HIP_MEMORY_SCOPE_AGENT);
        __hip_atomic_fetch_add(arrive, 1, __ATOMIC_ACQ_REL,
                               __HIP_MEMORY_SCOPE_AGENT);
        while (__hip_atomic_load(arrive, __ATOMIC_ACQUIRE,
                                 __HIP_MEMORY_SCOPE_AGENT) < NBLK)
            __builtin_amdgcn_s_sleep(2);
        __threadfence();                 // acquire: inv L1/L2
    }
    __syncthreads();
}

#define PREP_TOPK 256
#define PREP_W    1024
#define PREP_F1T  256
// virtual prep units: [0,256) topk | [256,1280) W | [1280,1536) f1t

__device__ __forceinline__ void prep_virtual(int vb, int t,
                                             const float* __restrict__ f1,
                                             const float* __restrict__ W,
                                             int* __restrict__ idx,
                                             u16* __restrict__ Wb,
                                             u16* __restrict__ W1b,
                                             u16* __restrict__ f1t) {
    if (vb < PREP_TOPK) {
        // ---- top-16 (wave/row, registers, exact fp32) ----
        const int lane = t & 63;
        const int row  = vb * 4 + (t >> 6);
        float v[16];
        const float* src = f1 + row * NDIM + lane;
        #pragma unroll
        for (int j = 0; j < 16; ++j) v[j] = src[j * 64];
        for (int sel = 0; sel < TK; ++sel) {
            float best = -3.402823466e38f; int bg = 0x7fffffff;
            #pragma unroll
            for (int j = 0; j < 16; ++j)
                if (v[j] > best) { best = v[j]; bg = j * 64 + lane; }
            #pragma unroll
            for (int s = 1; s < 64; s <<= 1) {
                float ov = __shfl_xor(best, s);
                int   og = __shfl_xor(bg, s);
                if (ov > best || (ov == best && og < bg)) { best = ov; bg = og; }
            }
            if (lane == sel) idx[row * TK + sel] = bg;
            #pragma unroll
            for (int j = 0; j < 16; ++j)
                if (bg == j * 64 + lane) v[j] = -3.402823466e38f;
        }
    } else if (vb < PREP_TOPK + PREP_W) {
        // ---- W-path: one virtual block per output row o ----
        const int o = vb - PREP_TOPK;                // 0..1023
        const float* wrow = W + (size_t)o * 16384;
        u16* wbrow = Wb + (size_t)o * KPOS;
        // pos half: contiguous permutation, coalesced read+write
        #pragma unroll
        for (int j = 0; j < 4; ++j) {
            const int v = j * 2048 + t * 8;              // pos-flat index
            const int u = ((v >> 5) << 6) + 32 + (v & 31);
            float4 a = *(const float4*)(wrow + u);
            float4 b = *(const float4*)(wrow + u + 4);
            u16x8 ov;
            ov[0] = f2bf(a.x); ov[1] = f2bf(a.y); ov[2] = f2bf(a.z); ov[3] = f2bf(a.w);
            ov[4] = f2bf(b.x); ov[5] = f2bf(b.y); ov[6] = f2bf(b.z); ov[7] = f2bf(b.w);
            *(u16x8*)(wbrow + v) = ov;
        }
        // rep half: reduce over tt
        #pragma unroll
        for (int h = 0; h < 2; ++h) {
            const int kr = h * 256 + t;        // 0..511
            const int nl = kr >> 5, e = kr & 31;
            const float* base = wrow + nl * 1024 + e;
            float s = 0.f;
            #pragma unroll
            for (int tt = 0; tt < 16; ++tt) s += base[tt * 64];
            W1b[o * KREP + kr] = f2bf(s);
        }
    } else {
        // ---- f1 -> f1t bf16 transpose (w-major, kh half-swapped) ----
        const int gb = vb - PREP_TOPK - PREP_W;      // 0..255
        const int unit = t >> 5;               // 0..7
        const int w = t & 31;
        const int rq = gb * 8 + unit;          // 0..2047
        const int row = rq >> 1, q = rq & 1;
        const float* src = f1 + row * NDIM + q * 512;
        const int swp = ((w >> 2) & 1) * 8;
        u16 tmp[16];
        #pragma unroll
        for (int kh = 0; kh < 16; ++kh)
            tmp[kh ^ swp] = f2bf(src[kh * 32 + w]);   // coalesced per-kh across lanes
        u16* dst = f1t + ((size_t)row * 2 + q) * 512 + w * 16;
        *(u16x8*)(dst)     = *(u16x8*)(tmp);
        *(u16x8*)(dst + 8) = *(u16x8*)(tmp + 8);
    }
}

// ---------------------------------------------------------------------------
// Fused kernel: prep (3 virtual units) -> global_barrier -> gemm (r17
// verbatim: 128x128 tile, BK=64, m=f&7 XCD colocation, A+B LDS dbuf, ONE
// barrier/iter, atomic scatter epilogue) -> global_barrier -> finalize.
// ---------------------------------------------------------------------------
#define BM 128
#define BN 128
#define BK 64
#define KITERS 34

__global__ __launch_bounds__(256, 2) void fused_kernel(const float* __restrict__ f1,
                                                       const float* __restrict__ W,
                                                       const float* __restrict__ bias,
                                                       int* __restrict__ idx,
                                                       u16* __restrict__ Wb,
                                                       u16* __restrict__ W1b,
                                                       u16* __restrict__ f1t,
                                                       float* __restrict__ out) {
    __shared__ __align__(16) u16 As[2][BM * BK];   // 2x16KB
    __shared__ __align__(16) u16 Bs[2][16 * 512];  // 2x16KB
    __shared__ int idxL[256];

    const int f = blockIdx.x;            // 0..511
    const int t = threadIdx.x;

    // ================= phase 1: prep (3 virtual units, stride 512) =======
    #pragma unroll 1
    for (int i = 0; i < 3; ++i)
        prep_virtual(f + NBLK * i, t, f1, W, idx, Wb, W1b, f1t);

    global_barrier(&g_ctr1, &g_ctr2);

    // ================= phase 2: gemm (r17 verbatim) ======================
    {
        const int m = f & 7;                 // XCD-colocated output-row group
        const int g = f >> 3;
        const int n = g & 15;
        const int z = g >> 4;                // 0..3
        const int lane = t & 63;
        const int wave = t >> 6;             // 0..3 == B-staging ci
        const int wm   = (wave >> 1) * 64;
        const int wn   = (wave & 1) * 64;
        const int quad = lane >> 4;
        const int l16  = lane & 15;
        const int sw   = l16 & 7;            // A-read chunk XOR key
        const int o0 = m * BM;
        const int n0 = n * BN;
        const int nb0 = n * 4;               // first batch of this tile
        const int kb = z * 2048;             // pos k-offset
        const int nl0 = z * 4;

        // preload this block's idx slice: idxL[bl*64 + nlz*16 + tt]
        {
            const int bl = t >> 6, nlz = (t >> 4) & 3, tt = t & 15;
            idxL[t] = idx[((nb0 + bl) * 16 + nl0 + nlz) * TK + tt];
        }

        f32x4 acc[4][4] = {};

        // A staging addresses: slot (row=32c+rA, chunk c8) holds chunk c8^(rA&7)
        const int rA = t >> 3;               // 0..31
        const int c8 = t & 7;
        const int csw = (c8 ^ (rA & 7)) * 8;
        const u16* gApos = Wb + (size_t)(o0 + rA) * KPOS + kb + csw;
        const u16* gArep = W1b + (size_t)(o0 + rA) * KREP + z * 128 + csw;
        const int ipbp = kb >> 4;            // z*128
        const int ipbr = z * 8;

        // stage iteration `it` into buffer `nb`: it<32 = pos, {32,33} = rep
        auto stage = [&](int it, int nb) {
            u16* lA = As[nb] + t * 8;
            int rows[4], qp;
            if (it < 32) {
                const int k0 = it * BK;
                #pragma unroll
                for (int c = 0; c < 4; ++c)
                    load_lds_16B(gApos + (size_t)(c * 32) * KPOS + k0, lA + c * 2048);
                const int ip = ipbp + it * 4 + wave;
                qp = ip & 1;
                const int nlz = (ip >> 5) & 3, tt = (ip >> 1) & 15;
                #pragma unroll
                for (int bl = 0; bl < 4; ++bl)
                    rows[bl] = idxL[bl * 64 + nlz * 16 + tt];
            } else {
                const int k0 = (it - 32) * BK;
                #pragma unroll
                for (int c = 0; c < 4; ++c)
                    load_lds_16B(gArep + (size_t)(c * 32) * KREP + k0, lA + c * 2048);
                const int ip = ipbr + (it - 32) * 4 + wave;
                qp = ip & 1;
                const int nlr = ip >> 1;
                #pragma unroll
                for (int bl = 0; bl < 4; ++bl)
                    rows[bl] = (nb0 + bl) * 16 + nlr;
            }
            #pragma unroll
            for (int bl = 0; bl < 4; ++bl)
                load_lds_16B(f1t + ((size_t)rows[bl] * 2 + qp) * 512 + lane * 8,
                             Bs[nb] + (wave * 4 + bl) * 512);
        };

        __syncthreads();        // idxL visible before first stage reads it
        stage(0, 0);
        __syncthreads();        // drain prologue DMA

        for (int it = 0; it < KITERS; ++it) {
            const int cur = it & 1;
            if (it + 1 < KITERS) stage(it + 1, 1 - cur);

            #pragma unroll
            for (int ks = 0; ks < 2; ++ks) {
                bf16x8 af[4], bfr[4];
                #pragma unroll
                for (int mt = 0; mt < 4; ++mt) {
                    u16x8 bits = *(const u16x8*)(As[cur] + (wm + mt * 16 + l16) * BK
                                                    + (((ks * 4 + quad) ^ sw) * 8));
                    af[mt] = __builtin_bit_cast(bf16x8, bits);
                }
                const int ci2 = ks * 2 + (quad >> 1);
                const int qh  = quad & 1;
                #pragma unroll
                for (int nt = 0; nt < 4; ++nt) {
                    const int nn = wn + nt * 16 + l16;
                    const int blocf = nn >> 5, w = nn & 31;
                    u16x8 bits = *(const u16x8*)(Bs[cur] + (ci2 * 4 + blocf) * 512 + w * 16
                                                    + ((qh ^ ((w >> 2) & 1)) * 8));
                    bfr[nt] = __builtin_bit_cast(bf16x8, bits);
                }
                #pragma unroll
                for (int mt = 0; mt < 4; ++mt)
                    #pragma unroll
                    for (int nt = 0; nt < 4; ++nt)
                        acc[mt][nt] = __builtin_amdgcn_mfma_f32_16x16x32_bf16(
                            af[mt], bfr[nt], acc[mt][nt], 0, 0, 0);
            }
            __syncthreads();    // one barrier per iter: releases buf[cur] AND
                                // drains the it+1 DMAs (vmcnt(0))
        }

        // epilogue: C/D row=quad*4+reg, col=l16; atomic-accumulate at final
        // scattered position: out[(b*16+(o>>6))*2048 + (o&63)*32 + w]
        #pragma unroll
        for (int nt = 0; nt < 4; ++nt) {
            const int nn = n0 + wn + nt * 16 + l16;
            const int bb = nn >> 5, w = nn & 31;
            #pragma unroll
            for (int mt = 0; mt < 4; ++mt) {
                #pragma unroll
                for (int r = 0; r < 4; ++r) {
                    const int o = o0 + wm + mt * 16 + quad * 4 + r;
                    unsafeAtomicAdd(out + (size_t)(bb * 16 + (o >> 6)) * 2048
                                        + (o & 63) * 32 + w,
                                    acc[mt][nt][r]);
                }
            }
        }
    }

    global_barrier(&g_ctr2, &g_ctr1);

    // ================= phase 3: finalize (4 virtual units) ===============
    #pragma unroll 1
    for (int i = 0; i < 4; ++i) {
        const int vb = f + NBLK * i;                 // 0..2047
        const int tid = vb * 256 + t;
        const int p = tid * 4;
        const int o = ((p >> 11) & 15) * 64 + ((p & 2047) >> 5);
        const float bv = bias[o];
        float4 x = *(float4*)(out + p);
        x.x = fmaxf(x.x + bv, 0.f);
        x.y = fmaxf(x.y + bv, 0.f);
        x.z = fmaxf(x.z + bv, 0.f);
        x.w = fmaxf(x.w + bv, 0.f);
        *(float4*)(out + p) = x;
    }
}

// ---------------------------------------------------------------------------
extern "C" void kernel_launch(void* const* d_in, const int* in_sizes, int n_in,
                              void* d_out, int out_size, void* d_ws, size_t ws_size,
                              hipStream_t stream) {
    const float* f1   = (const float*)d_in[0];   // [1024][1024]
    const float* Wc   = (const float*)d_in[1];   // [1024][1024][16][1]
    const float* bias = (const float*)d_in[2];   // [1024]
    float* out = (float*)d_out;                  // [1024][2048]

    // workspace layout (bytes):
    //   idx:  0         (64KB)
    //   Wb:   65536     (1024*8192*2 = 16MB)
    //   W1b:  16842752  (1024*512*2  = 1MB)
    //   f1t:  17891328  (1024*2*512*2 = 2MB)
    int* idx = (int*)d_ws;
    u16* Wb  = (u16*)((char*)d_ws + 65536);
    u16* W1b = (u16*)((char*)d_ws + 16842752);
    u16* f1t = (u16*)((char*)d_ws + 17891328);

    // zero the accumulator memory-side (graph-legal; avoids dirty-L2 zeros)
    hipMemsetAsync(out, 0, (size_t)NDIM * NCOL * sizeof(float), stream);
    fused_kernel<<<NBLK, 256, 0, stream>>>(f1, Wc, bias, idx, Wb, W1b, f1t, out);
}

// Round 10
// 180.143 us; speedup vs baseline: 2.3557x; 2.3557x over previous
//
#include <hip/hip_runtime.h>
#include <stdint.h>

// y[b,o,w] = relu(bias[o] + sum_{i,kh} W[o,i,kh] * x[b,i,kh,w])
// q=i&3 split: q<2 ("rep") -> pre-sum W over tt => K=512; q>=2 ("pos") keeps
// the gathered K=8192. r22: 3-blocks/CU residency at UNCHANGED iter count.
// r12-class pipeline (BK=64, A LDS-dbuf DMA, one full drain per iter) but Bs
// single-buffered with T14 reg-split: loadB(it+1)->regs during compute(it);
// raw s_barrier (readers done, NO vmcnt drain); ds_write regs->Bs;
// __syncthreads (drains A(it+1) DMA issued a full compute-phase earlier).
// LDS 49.7KB -> 3 blocks/CU (12 waves, was 8). z=8 (grid 1024, 17 iters).
// m=f&7 XCD colocation kept (FETCH-verified r15/r17).
// 3 dispatches: prep -> gemm -> finalize. (r21 decomposition: harness fixed
// ~75us, prep+fin ~30us -> gemm is the only live lever.)

#define NDIM 1024
#define TK   16
#define KPOS 8192    // pos K: 512 i's * 16 kh
#define KREP 512     // rep K: 32 (nl,q) * 16 kh
#define NCOL 2048    // 64 batches * 32 width

typedef unsigned short u16;
typedef uint32_t u32;
typedef u16   u16x8  __attribute__((ext_vector_type(8)));
typedef __bf16 bf16x8 __attribute__((ext_vector_type(8)));
typedef float  f32x4  __attribute__((ext_vector_type(4)));

__device__ __forceinline__ u16 f2bf(float x) {
    union { float f; unsigned u; } v; v.f = x;
    unsigned r = 0x7FFFu + ((v.u >> 16) & 1u);   // round-to-nearest-even
    return (u16)((v.u + r) >> 16);
}

// async global->LDS, 16B/lane; LDS dest is wave-uniform base + lane*16
__device__ __forceinline__ void load_lds_16B(const u16* g, u16* l) {
    __builtin_amdgcn_global_load_lds(
        (__attribute__((address_space(1))) void*)(uintptr_t)g,
        (__attribute__((address_space(3))) void*)(unsigned)(uintptr_t)l,
        16, 0, 0);
}

// ---------------------------------------------------------------------------
// Kernel 1 (fused, grid-partitioned):  [r17 verbatim, verified]
//   [0,256):      top-16 per row (wave/row, registers, exact fp32)
//   [256,768):    zero d_out (512 blocks x 16KB)
//   [768,1792):   W-path, one block per o (pos permutation + rep tt-reduce)
//   [1792,2048):  f1t[row][q][w][kh^swp] = bf16(f1[row, q*512+kh*32+w]),
//                 swp = 8*((w>>2)&1)
// ---------------------------------------------------------------------------
#define PREP_TOPK 256
#define PREP_ZERO 512
#define PREP_W    1024
#define PREP_F1T  256

__global__ __launch_bounds__(256) void prep_kernel(const float* __restrict__ f1,
                                                   const float* __restrict__ W,
                                                   int* __restrict__ idx,
                                                   u16* __restrict__ Wb,
                                                   u16* __restrict__ W1b,
                                                   u16* __restrict__ f1t,
                                                   float* __restrict__ out) {
    const int bid = blockIdx.x;
    const int t = threadIdx.x;
    if (bid < PREP_TOPK) {
        // ---- top-16 ----
        const int lane = t & 63;
        const int row  = bid * 4 + (t >> 6);
        float v[16];
        const float* src = f1 + row * NDIM + lane;
        #pragma unroll
        for (int j = 0; j < 16; ++j) v[j] = src[j * 64];
        for (int sel = 0; sel < TK; ++sel) {
            float best = -3.402823466e38f; int bg = 0x7fffffff;
            #pragma unroll
            for (int j = 0; j < 16; ++j)
                if (v[j] > best) { best = v[j]; bg = j * 64 + lane; }
            #pragma unroll
            for (int s = 1; s < 64; s <<= 1) {
                float ov = __shfl_xor(best, s);
                int   og = __shfl_xor(bg, s);
                if (ov > best || (ov == best && og < bg)) { best = ov; bg = og; }
            }
            if (lane == sel) idx[row * TK + sel] = bg;
            #pragma unroll
            for (int j = 0; j < 16; ++j)
                if (bg == j * 64 + lane) v[j] = -3.402823466e38f;
        }
    } else if (bid < PREP_TOPK + PREP_ZERO) {
        // ---- zero the 8MB output accumulator ----
        const int zb = bid - PREP_TOPK;
        f32x4 z = {0.f, 0.f, 0.f, 0.f};
        float* p = out + (size_t)zb * 4096 + t * 16;
        #pragma unroll
        for (int j = 0; j < 4; ++j) *(f32x4*)(p + j * 4) = z;
    } else if (bid < PREP_TOPK + PREP_ZERO + PREP_W) {
        // ---- W-path: one block per output row o ----
        const int o = bid - PREP_TOPK - PREP_ZERO;   // 0..1023
        const float* wrow = W + (size_t)o * 16384;
        u16* wbrow = Wb + (size_t)o * KPOS;
        // pos half: contiguous permutation, coalesced read+write
        #pragma unroll
        for (int j = 0; j < 4; ++j) {
            const int v = j * 2048 + t * 8;              // pos-flat index
            const int u = ((v >> 5) << 6) + 32 + (v & 31);
            float4 a = *(const float4*)(wrow + u);
            float4 b = *(const float4*)(wrow + u + 4);
            u16x8 ov;
            ov[0] = f2bf(a.x); ov[1] = f2bf(a.y); ov[2] = f2bf(a.z); ov[3] = f2bf(a.w);
            ov[4] = f2bf(b.x); ov[5] = f2bf(b.y); ov[6] = f2bf(b.z); ov[7] = f2bf(b.w);
            *(u16x8*)(wbrow + v) = ov;
        }
        // rep half: reduce over tt
        #pragma unroll
        for (int h = 0; h < 2; ++h) {
            const int kr = h * 256 + t;        // 0..511
            const int nl = kr >> 5, e = kr & 31;
            const float* base = wrow + nl * 1024 + e;
            float s = 0.f;
            #pragma unroll
            for (int tt = 0; tt < 16; ++tt) s += base[tt * 64];
            W1b[o * KREP + kr] = f2bf(s);
        }
    } else {
        // ---- f1 -> f1t bf16 transpose (w-major, kh half-swapped by w>>2&1) ----
        const int gb = bid - PREP_TOPK - PREP_ZERO - PREP_W;   // 0..255
        const int unit = t >> 5;               // 0..7
        const int w = t & 31;
        const int rq = gb * 8 + unit;          // 0..2047
        const int row = rq >> 1, q = rq & 1;
        const float* src = f1 + row * NDIM + q * 512;
        const int swp = ((w >> 2) & 1) * 8;
        u16 tmp[16];
        #pragma unroll
        for (int kh = 0; kh < 16; ++kh)
            tmp[kh ^ swp] = f2bf(src[kh * 32 + w]);   // coalesced per-kh across lanes
        u16* dst = f1t + ((size_t)row * 2 + q) * 512 + w * 16;
        *(u16x8*)(dst)     = *(u16x8*)(tmp);
        *(u16x8*)(dst + 8) = *(u16x8*)(tmp + 8);
    }
}

// ---------------------------------------------------------------------------
// Kernel 2: bf16 MFMA GEMM, 128x128 tile, BK=64, 1024 blocks:
//   m = f&7 (XCD), g = f>>3, n = g&15, z = g>>4 (K-eighth).
// 17 iters/block: 16 pos (z's eighth of KPOS) + 1 rep (z's eighth of KREP).
// A: LDS double-buffer via global_load_lds (row&7 chunk XOR swizzle) — r12
//    staging verbatim with z=8 offsets.
// B: single Bs buffer + register split: loadB(it+1)->regs (4x16B global,
//    latency hidden under compute(it)); after raw s_barrier (readers done),
//    ds_write regs->Bs; __syncthreads drains the A(it+1) DMA.
// LDS 49.7KB -> 3 blocks/CU. Atomic scatter epilogue (8 z-contribs, XCD L2).
// ---------------------------------------------------------------------------
#define BM 128
#define BN 128
#define BK 64
#define KITERS 17

__global__ __launch_bounds__(256, 3) void gemm_kernel(const u16* __restrict__ Ap,
                                                      const u16* __restrict__ A1,
                                                      const u16* __restrict__ f1t,
                                                      const int* __restrict__ idx,
                                                      float* __restrict__ out) {
    __shared__ __align__(16) u16 As[2][BM * BK];   // 2x16KB, [row][chunk^(row&7)]
    __shared__ __align__(16) u16 Bs[16 * 512];     // 16KB, [ci][bloc][w][half]
    __shared__ int idxL[128];                       // [bl][nlz][tt]
    const int f = blockIdx.x;            // 0..1023
    const int m = f & 7;                 // XCD-colocated output-row group
    const int g = f >> 3;
    const int n = g & 15;
    const int z = g >> 4;                // 0..7
    const int t    = threadIdx.x;
    const int lane = t & 63;
    const int wave = t >> 6;             // 0..3 == B-staging ci
    const int wm   = (wave >> 1) * 64;
    const int wn   = (wave & 1) * 64;
    const int quad = lane >> 4;
    const int l16  = lane & 15;
    const int sw   = l16 & 7;            // A-read chunk XOR key
    const int o0 = m * BM;
    const int n0 = n * BN;
    const int nb0 = n * 4;               // first batch of this tile

    // preload this block's idx slice: idxL[bl*32 + nlz*16 + tt], nl = z*2+nlz
    if (t < 128) {
        const int bl = t >> 5, nlz = (t >> 4) & 1, tt = t & 15;
        idxL[t] = idx[((nb0 + bl) * 16 + z * 2 + nlz) * TK + tt];
    }

    f32x4 acc[4][4] = {};

    // A staging addresses: slot (row=32c+rA, chunk c8) holds chunk c8^(rA&7)
    const int rA = t >> 3;               // 0..31
    const int c8 = t & 7;
    const int csw = (c8 ^ (rA & 7)) * 8;
    const u16* gApos = Ap + (size_t)(o0 + rA) * KPOS + z * 1024 + csw;
    const u16* gArep = A1 + (size_t)(o0 + rA) * KREP + z * 64 + csw;

    // stage A for iteration `it` into buffer `nb`: it<16 = pos, it==16 = rep
    auto stageA = [&](int it, int nb) {
        u16* lA = As[nb] + t * 8;
        if (it < 16) {
            const int k0 = it * BK;
            #pragma unroll
            for (int c = 0; c < 4; ++c)
                load_lds_16B(gApos + (size_t)(c * 32) * KPOS + k0, lA + c * 2048);
        } else {
            #pragma unroll
            for (int c = 0; c < 4; ++c)
                load_lds_16B(gArep + (size_t)(c * 32) * KREP, lA + c * 2048);
        }
    };

    // load the 4 B rows of iteration `it` (wave = k16-unit ci) into regs
    u16x8 breg[4];
    auto loadB = [&](int it) {
        int rows[4], qp;
        if (it < 16) {
            const int ip = z * 64 + it * 4 + wave;     // global pos k16-unit
            qp = ip & 1;
            const int nlz = (ip >> 5) & 1, tt = (ip >> 1) & 15;
            #pragma unroll
            for (int bl = 0; bl < 4; ++bl)
                rows[bl] = idxL[bl * 32 + nlz * 16 + tt];
        } else {
            const int ip = z * 4 + wave;               // global rep unit
            qp = ip & 1;
            const int nlr = ip >> 1;                   // z*2 + (wave>>1)
            #pragma unroll
            for (int bl = 0; bl < 4; ++bl)
                rows[bl] = (nb0 + bl) * 16 + nlr;
        }
        #pragma unroll
        for (int bl = 0; bl < 4; ++bl)
            breg[bl] = *(const u16x8*)(f1t + ((size_t)rows[bl] * 2 + qp) * 512
                                           + lane * 8);
    };
    auto writeB = [&]() {
        #pragma unroll
        for (int bl = 0; bl < 4; ++bl)
            *(u16x8*)(Bs + (wave * 4 + bl) * 512 + lane * 8) = breg[bl];
    };

    // compute one BK=64 iteration from As buffer + Bs (r12 fragment math)
    auto compute = [&](const u16* AsX) {
        #pragma unroll
        for (int ks = 0; ks < 2; ++ks) {
            bf16x8 af[4], bfr[4];
            #pragma unroll
            for (int mt = 0; mt < 4; ++mt) {
                u16x8 bits = *(const u16x8*)(AsX + (wm + mt * 16 + l16) * BK
                                                + (((ks * 4 + quad) ^ sw) * 8));
                af[mt] = __builtin_bit_cast(bf16x8, bits);
            }
            const int ci2 = ks * 2 + (quad >> 1);
            const int qh  = quad & 1;
            #pragma unroll
            for (int nt = 0; nt < 4; ++nt) {
                const int nn = wn + nt * 16 + l16;
                const int blocf = nn >> 5, w = nn & 31;
                u16x8 bits = *(const u16x8*)(Bs + (ci2 * 4 + blocf) * 512 + w * 16
                                                + ((qh ^ ((w >> 2) & 1)) * 8));
                bfr[nt] = __builtin_bit_cast(bf16x8, bits);
            }
            #pragma unroll
            for (int mt = 0; mt < 4; ++mt)
                #pragma unroll
                for (int nt = 0; nt < 4; ++nt)
                    acc[mt][nt] = __builtin_amdgcn_mfma_f32_16x16x32_bf16(
                        af[mt], bfr[nt], acc[mt][nt], 0, 0, 0);
        }
    };

    __syncthreads();        // idxL visible
    loadB(0);
    stageA(0, 0);
    writeB();               // compiler inserts the vmcnt wait for breg
    __syncthreads();        // drains A(0) DMA + publishes Bs(0)

    for (int it = 0; it < KITERS; ++it) {
        const int cur = it & 1;
        if (it + 1 < KITERS) {
            loadB(it + 1);              // global->reg, covered by compute(it)
            stageA(it + 1, cur ^ 1);    // DMA, drained at end-of-iter sync
        }
        compute(As[cur]);
        if (it + 1 < KITERS) {
            // raw barrier: all waves done READING Bs (ds_reads retired before
            // MFMA consumption); no vmcnt drain here — A/B(it+1) stay in flight
            asm volatile("s_barrier" ::: "memory");
            writeB();                   // compiler waits vmcnt for breg only
            __syncthreads();            // vmcnt(0): A(it+1) drained (issued a
                                        // full compute-phase ago) + Bs visible
        }
    }

    // epilogue: C/D row=quad*4+reg, col=l16; atomic-accumulate at final
    // scattered position: out[(b*16+(o>>6))*2048 + (o&63)*32 + w]
    #pragma unroll
    for (int nt = 0; nt < 4; ++nt) {
        const int nn = n0 + wn + nt * 16 + l16;
        const int bb = nn >> 5, w = nn & 31;
        #pragma unroll
        for (int mt = 0; mt < 4; ++mt) {
            #pragma unroll
            for (int r = 0; r < 4; ++r) {
                const int o = o0 + wm + mt * 16 + quad * 4 + r;
                unsafeAtomicAdd(out + (size_t)(bb * 16 + (o >> 6)) * 2048
                                    + (o & 63) * 32 + w,
                                acc[mt][nt][r]);
            }
        }
    }
}

// ---------------------------------------------------------------------------
// Kernel 3: in-place bias + relu on the accumulated output.
// ---------------------------------------------------------------------------
__global__ __launch_bounds__(256) void finalize_kernel(float* __restrict__ out,
                                                       const float* __restrict__ bias) {
    const int tid = blockIdx.x * 256 + threadIdx.x;
    const int f = tid * 4;
    const int o = ((f >> 11) & 15) * 64 + ((f & 2047) >> 5);
    const float bv = bias[o];
    float4 x = *(float4*)(out + f);
    x.x = fmaxf(x.x + bv, 0.f);
    x.y = fmaxf(x.y + bv, 0.f);
    x.z = fmaxf(x.z + bv, 0.f);
    x.w = fmaxf(x.w + bv, 0.f);
    *(float4*)(out + f) = x;
}

// ---------------------------------------------------------------------------
extern "C" void kernel_launch(void* const* d_in, const int* in_sizes, int n_in,
                              void* d_out, int out_size, void* d_ws, size_t ws_size,
                              hipStream_t stream) {
    const float* f1   = (const float*)d_in[0];   // [1024][1024]
    const float* Wc   = (const float*)d_in[1];   // [1024][1024][16][1]
    const float* bias = (const float*)d_in[2];   // [1024]
    float* out = (float*)d_out;                  // [1024][2048]

    // workspace layout (bytes):
    //   idx:  0         (64KB)
    //   Wb:   65536     (1024*8192*2 = 16MB)
    //   W1b:  16842752  (1024*512*2  = 1MB)
    //   f1t:  17891328  (1024*2*512*2 = 2MB)
    int* idx = (int*)d_ws;
    u16* Wb  = (u16*)((char*)d_ws + 65536);
    u16* W1b = (u16*)((char*)d_ws + 16842752);
    u16* f1t = (u16*)((char*)d_ws + 17891328);

    prep_kernel<<<PREP_TOPK + PREP_ZERO + PREP_W + PREP_F1T,
                  256, 0, stream>>>(f1, Wc, idx, Wb, W1b, f1t, out);
    gemm_kernel<<<1024, 256, 0, stream>>>(Wb, W1b, f1t, idx, out);
    finalize_kernel<<<(NDIM * NCOL) / (4 * 256), 256, 0, stream>>>(out, bias);
}